// Round 3
// baseline (5571.757 us; speedup 1.0000x reference)
//
#include <hip/hip_runtime.h>
#include <hip/hip_bf16.h>
#include <math.h>

typedef __hip_bfloat16 bf16;

static __device__ __forceinline__ float ldv(float v) { return v; }
static __device__ __forceinline__ float ldv(bf16 v) { return __bfloat162float(v); }
template <typename T> static __device__ __forceinline__ T stv(float v);
template <> __device__ __forceinline__ float stv<float>(float v) { return v; }
template <> __device__ __forceinline__ bf16 stv<bf16>(float v) { return __float2bfloat16(v); }

#define NPIX 16384  // 128*128 spatial per channel

// ---------------------------------------------------------------------------
// Generalized pointwise 1x1 conv (per-batch GEMM), fp32 in, OutT out:
//   out[b, orow0+r, p] = sum_ci w[wrow0+r, ci] * x[b, ci, p]
// grid: (64, Crows/8, B), block 256. Each thread: 1 pixel, 8 output rows.
// ---------------------------------------------------------------------------
template <typename OutT>
__global__ __launch_bounds__(256) void pw_conv(const float* __restrict__ x,
                                               const float* __restrict__ w,
                                               OutT* __restrict__ out,
                                               int Cin, int wrow0,
                                               int outCtot, int orow0)
{
    __shared__ float wl[8 * 768];
    const int tid = threadIdx.x;
    const int p   = blockIdx.x * 256 + tid;
    const int co0 = blockIdx.y * 8;
    const int b   = blockIdx.z;

    for (int idx = tid; idx < 8 * Cin; idx += 256) {
        int k = idx / Cin, ci = idx - k * Cin;
        wl[k * Cin + ci] = w[(size_t)(wrow0 + co0 + k) * Cin + ci];
    }
    __syncthreads();

    float acc[8];
#pragma unroll
    for (int k = 0; k < 8; ++k) acc[k] = 0.f;

    const float* xb = x + (size_t)b * Cin * NPIX + p;
    for (int ci = 0; ci < Cin; ci += 4) {
        float x0 = xb[(size_t)(ci + 0) * NPIX];
        float x1 = xb[(size_t)(ci + 1) * NPIX];
        float x2 = xb[(size_t)(ci + 2) * NPIX];
        float x3 = xb[(size_t)(ci + 3) * NPIX];
#pragma unroll
        for (int k = 0; k < 8; ++k) {
            const float4 wv = *reinterpret_cast<const float4*>(&wl[k * Cin + ci]);
            acc[k] += x0 * wv.x + x1 * wv.y + x2 * wv.z + x3 * wv.w;
        }
    }
#pragma unroll
    for (int k = 0; k < 8; ++k)
        out[((size_t)b * outCtot + (orow0 + co0 + k)) * NPIX + p] = stv<OutT>(acc[k]);
}

// ---------------------------------------------------------------------------
// Two-input projection GEMM (replaces concat + 1x1 conv), bf16 in, fp32 out:
//   out[b,co,p] = sum_ci<384 w[co,ci]*inA[b,ci,p] + sum_ci<384 w[co,384+ci]*inB[b,ci,p]
// grid: (64, 48, 4), block 256.
// ---------------------------------------------------------------------------
__global__ __launch_bounds__(256) void proj_conv(const bf16* __restrict__ inA,
                                                 const bf16* __restrict__ inB,
                                                 const float* __restrict__ w,
                                                 float* __restrict__ out)
{
    __shared__ float wl[8 * 768];
    const int tid = threadIdx.x;
    const int p   = blockIdx.x * 256 + tid;
    const int co0 = blockIdx.y * 8;
    const int b   = blockIdx.z;

    for (int idx = tid; idx < 8 * 768; idx += 256) {
        int k = idx / 768, ci = idx - k * 768;
        wl[k * 768 + ci] = w[(size_t)(co0 + k) * 768 + ci];
    }
    __syncthreads();

    float acc[8];
#pragma unroll
    for (int k = 0; k < 8; ++k) acc[k] = 0.f;

    const bf16* ab = inA + (size_t)b * 384 * NPIX + p;
    for (int ci = 0; ci < 384; ci += 4) {
        float x0 = ldv(ab[(size_t)(ci + 0) * NPIX]);
        float x1 = ldv(ab[(size_t)(ci + 1) * NPIX]);
        float x2 = ldv(ab[(size_t)(ci + 2) * NPIX]);
        float x3 = ldv(ab[(size_t)(ci + 3) * NPIX]);
#pragma unroll
        for (int k = 0; k < 8; ++k) {
            const float4 wv = *reinterpret_cast<const float4*>(&wl[k * 768 + ci]);
            acc[k] += x0 * wv.x + x1 * wv.y + x2 * wv.z + x3 * wv.w;
        }
    }
    const bf16* bb = inB + (size_t)b * 384 * NPIX + p;
    for (int ci = 0; ci < 384; ci += 4) {
        float x0 = ldv(bb[(size_t)(ci + 0) * NPIX]);
        float x1 = ldv(bb[(size_t)(ci + 1) * NPIX]);
        float x2 = ldv(bb[(size_t)(ci + 2) * NPIX]);
        float x3 = ldv(bb[(size_t)(ci + 3) * NPIX]);
#pragma unroll
        for (int k = 0; k < 8; ++k) {
            const float4 wv = *reinterpret_cast<const float4*>(&wl[k * 768 + 384 + ci]);
            acc[k] += x0 * wv.x + x1 * wv.y + x2 * wv.z + x3 * wv.w;
        }
    }
#pragma unroll
    for (int k = 0; k < 8; ++k)
        out[((size_t)b * 384 + (co0 + k)) * NPIX + p] = acc[k];
}

// ---------------------------------------------------------------------------
// Depthwise 3x3, pad=1, optional exact GELU, with channel-offset remapping.
// grid: (64, C_launch, B)
// ---------------------------------------------------------------------------
template <typename InT, typename OutT>
__global__ __launch_bounds__(256) void dw3x3(const InT* __restrict__ in,
                                             const float* __restrict__ w,
                                             OutT* __restrict__ out,
                                             int inCtot, int inCoff, int wcoff,
                                             int outCtot, int outCoff,
                                             int applyGelu)
{
    const int tid = threadIdx.x;
    const int p = blockIdx.x * 256 + tid;
    const int c = blockIdx.y;
    const int b = blockIdx.z;
    const int y = p >> 7;
    const int xx = p & 127;

    const InT* ib = in + ((size_t)b * inCtot + (inCoff + c)) * NPIX;
    float wv[9];
#pragma unroll
    for (int i = 0; i < 9; ++i) wv[i] = w[(wcoff + c) * 9 + i];

    float acc = 0.f;
#pragma unroll
    for (int dy = -1; dy <= 1; ++dy) {
        int yy = y + dy;
        if (yy < 0 || yy > 127) continue;
#pragma unroll
        for (int dx = -1; dx <= 1; ++dx) {
            int xc = xx + dx;
            if (xc < 0 || xc > 127) continue;
            acc += ldv(ib[yy * 128 + xc]) * wv[(dy + 1) * 3 + (dx + 1)];
        }
    }
    if (applyGelu) acc = 0.5f * acc * (1.0f + erff(acc * 0.70710678118654752f));
    out[((size_t)b * outCtot + (outCoff + c)) * NPIX + p] = stv<OutT>(acc);
}

// ---------------------------------------------------------------------------
// Per-head inv-L2-norm factors over qkv_head buffer (144 ch: q=0..47 k=48..95).
// grid: 2*4*48 = 384 blocks. inv layout: [which(2)][b(4)][c(48)].
// ---------------------------------------------------------------------------
__global__ __launch_bounds__(256) void l2norm_head(const bf16* __restrict__ qkvh,
                                                   float* __restrict__ inv)
{
    const int id = blockIdx.x;
    const int which = id / 192;
    const int rem = id - which * 192;
    const int b = rem / 48, c = rem - b * 48;
    const bf16* base = qkvh + ((size_t)b * 144 + which * 48 + c) * NPIX;

    float s = 0.f;
    for (int p = threadIdx.x; p < NPIX; p += 256) {
        float v = ldv(base[p]);
        s += v * v;
    }
#pragma unroll
    for (int off = 32; off; off >>= 1) s += __shfl_down(s, off, 64);
    __shared__ float partial[4];
    if ((threadIdx.x & 63) == 0) partial[threadIdx.x >> 6] = s;
    __syncthreads();
    if (threadIdx.x == 0) {
        float t = partial[0] + partial[1] + partial[2] + partial[3];
        inv[id] = 1.0f / fmaxf(sqrtf(t), 1e-12f);
    }
}

// ---------------------------------------------------------------------------
// Per-head attention logits: logits[b,i,j] = scale*invq[i]*invk[j]*<q_i,k_j>
// grid: (48, 4). One block: one q-row vs all 48 k-rows, length-16384 dots.
// ---------------------------------------------------------------------------
__global__ __launch_bounds__(256) void qk_logits_head(const bf16* __restrict__ qkvh,
                                                      const float* __restrict__ inv,
                                                      float* __restrict__ logits)
{
    const int i = blockIdx.x;
    const int b = blockIdx.y;
    const int tid = threadIdx.x;

    const bf16* qrow  = qkvh + ((size_t)b * 144 + i) * NPIX;
    const bf16* kbase = qkvh + ((size_t)b * 144 + 48) * NPIX;

    float acc[48];
#pragma unroll
    for (int j = 0; j < 48; ++j) acc[j] = 0.f;

    for (int p = tid; p < NPIX; p += 256) {
        float qv = ldv(qrow[p]);
#pragma unroll
        for (int j = 0; j < 48; ++j)
            acc[j] += qv * ldv(kbase[(size_t)j * NPIX + p]);
    }

    __shared__ float red[4][48];
    const int lane = tid & 63, wave = tid >> 6;
#pragma unroll
    for (int j = 0; j < 48; ++j) {
        float s = acc[j];
#pragma unroll
        for (int off = 32; off; off >>= 1) s += __shfl_down(s, off, 64);
        if (lane == 0) red[wave][j] = s;
    }
    __syncthreads();
    if (tid < 48) {
        float s = red[0][tid] + red[1][tid] + red[2][tid] + red[3][tid];
        float qn = inv[b * 48 + i];
        float kn = inv[192 + b * 48 + tid];
        logits[((size_t)b * 48 + i) * 48 + tid] = s * 0.14433756729740643f * qn * kn;
    }
}

// ---------------------------------------------------------------------------
// Per-head softmax + AV: attn[b, h*48+i, p] = sum_j softmax(logits[b,i,:])[j]*v_j[p]
// grid: (64, 48, 4)
// ---------------------------------------------------------------------------
__global__ __launch_bounds__(256) void softmax_av_head(const float* __restrict__ logits,
                                                       const bf16* __restrict__ qkvh,
                                                       bf16* __restrict__ attn, int h)
{
    const int tid = threadIdx.x;
    const int p = blockIdx.x * 256 + tid;
    const int i = blockIdx.y;
    const int b = blockIdx.z;

    __shared__ float arow[48];
    if (tid < 64) {
        float l = (tid < 48) ? logits[((size_t)b * 48 + i) * 48 + tid] : -1e30f;
        float m = l;
#pragma unroll
        for (int off = 32; off; off >>= 1) m = fmaxf(m, __shfl_xor(m, off, 64));
        float e = (tid < 48) ? expf(l - m) : 0.f;
        float s = e;
#pragma unroll
        for (int off = 32; off; off >>= 1) s += __shfl_xor(s, off, 64);
        if (tid < 48) arow[tid] = e / s;
    }
    __syncthreads();

    const bf16* vbase = qkvh + ((size_t)b * 144 + 96) * NPIX + p;
    float acc = 0.f;
#pragma unroll
    for (int j = 0; j < 48; ++j) acc += arow[j] * ldv(vbase[(size_t)j * NPIX]);
    attn[((size_t)b * 384 + h * 48 + i) * NPIX + p] = stv<bf16>(acc);
}

// ---------------------------------------------------------------------------
extern "C" void kernel_launch(void* const* d_in, const int* in_sizes, int n_in,
                              void* d_out, int out_size, void* d_ws, size_t ws_size,
                              hipStream_t stream) {
    const float* x       = (const float*)d_in[0];
    const float* w_qkv   = (const float*)d_in[1];
    const float* w_dw    = (const float*)d_in[2];
    const float* w_proj  = (const float*)d_in[3];
    const float* w_bs_pw = (const float*)d_in[4];
    const float* w_bs_dw = (const float*)d_in[5];
    float* out = (float*)d_out;

    // workspace layout — peak ≈138.5 MB (proven safe in R2), bf16 intermediates
    char* ws = (char*)d_ws;
    bf16* y_gelu = (bf16*)ws;                           //  50,331,648 B
    bf16* attn   = (bf16*)(ws + 50331648);              //  50,331,648 B
    bf16* qkvp   = (bf16*)(ws + 100663296);             //  18,874,368 B (head pw out)
    bf16* qkvd   = (bf16*)(ws + 119537664);             //  18,874,368 B (head dw out)
    float* inv   = (float*)(ws + 138412032);            //  1,536 B
    float* logits= (float*)(ws + 138416128);            //  36,864 B
    float* y1 = out;  // BSConv pw output (fp32) lives in d_out until proj overwrites

    dim3 blk(256);
    // BSConv branch: pw (fp32 into d_out) -> dw+GELU (bf16)
    pw_conv<float><<<dim3(64, 48, 4), blk, 0, stream>>>(x, w_bs_pw, y1, 384, 0, 384, 0);
    dw3x3<float, bf16><<<dim3(64, 384, 4), blk, 0, stream>>>(y1, w_bs_dw, y_gelu, 384, 0, 0, 384, 0, 1);

    // attention path, one head (48 q + 48 k + 48 v channels) at a time
    for (int h = 0; h < 8; ++h) {
        pw_conv<bf16><<<dim3(64, 6, 4), blk, 0, stream>>>(x, w_qkv, qkvp, 384, h * 48,       144, 0);
        pw_conv<bf16><<<dim3(64, 6, 4), blk, 0, stream>>>(x, w_qkv, qkvp, 384, 384 + h * 48, 144, 48);
        pw_conv<bf16><<<dim3(64, 6, 4), blk, 0, stream>>>(x, w_qkv, qkvp, 384, 768 + h * 48, 144, 96);
        dw3x3<bf16, bf16><<<dim3(64, 48, 4), blk, 0, stream>>>(qkvp, w_dw, qkvd, 144, 0,  h * 48,       144, 0,  0);
        dw3x3<bf16, bf16><<<dim3(64, 48, 4), blk, 0, stream>>>(qkvp, w_dw, qkvd, 144, 48, 384 + h * 48, 144, 48, 0);
        dw3x3<bf16, bf16><<<dim3(64, 48, 4), blk, 0, stream>>>(qkvp, w_dw, qkvd, 144, 96, 768 + h * 48, 144, 96, 0);
        l2norm_head<<<dim3(384), blk, 0, stream>>>(qkvd, inv);
        qk_logits_head<<<dim3(48, 4), blk, 0, stream>>>(qkvd, inv, logits);
        softmax_av_head<<<dim3(64, 48, 4), blk, 0, stream>>>(logits, qkvd, attn, h);
    }

    // projection over (attn ++ y_gelu) -> fp32 out
    proj_conv<<<dim3(64, 48, 4), blk, 0, stream>>>(attn, y_gelu, w_proj, out);
}

// Round 4
// 1991.787 us; speedup vs baseline: 2.7974x; 2.7974x over previous
//
#include <hip/hip_runtime.h>
#include <hip/hip_bf16.h>
#include <math.h>

typedef __hip_bfloat16 bf16;
typedef short bf16x8 __attribute__((ext_vector_type(8)));
typedef float f32x4 __attribute__((ext_vector_type(4)));

#define NPIX 16384  // 128*128 spatial per channel

static __device__ __forceinline__ float ldv(float v) { return v; }
static __device__ __forceinline__ float ldv(bf16 v) { return __bfloat162float(v); }
template <typename T> static __device__ __forceinline__ T stv(float v);
template <> __device__ __forceinline__ float stv<float>(float v) { return v; }
template <> __device__ __forceinline__ bf16 stv<bf16>(float v) { return __float2bfloat16(v); }

static __device__ __forceinline__ unsigned pack2f(float a, float b) {
    union { bf16 h; unsigned short u; } ua, ub;
    ua.h = __float2bfloat16(a); ub.h = __float2bfloat16(b);
    return (unsigned)ua.u | ((unsigned)ub.u << 16);
}

// ---------------------------------------------------------------------------
// MFMA pointwise GEMM. out[b, orow0+bm*48+r, p] = sum_k w[wrow0+bm*wrstride+r, k]*src(b,k,p)
// src(b,k,p) = srcA[b, k, p] for k<Ksplit else srcB[b, k-Ksplit, p].
// BM=48 (3 m-tiles), BN=128 (4 waves x 2 n-tiles), BK=32, mfma_f32_16x16x32_bf16.
// B-tile is transposed into LDS as [n][k] (row stride 40 shorts = 80 B: 16B-aligned,
// bank-conflict-reduced). A-tile (weights) staged fp32->bf16, natural [m][k].
// grid: (128, M/48, 4)
// ---------------------------------------------------------------------------
template <typename SrcT, typename OutT>
__global__ __launch_bounds__(256) void gemm48(const SrcT* __restrict__ srcA,
                                              const SrcT* __restrict__ srcB, int Ksplit,
                                              const float* __restrict__ w, int K,
                                              int wrow0, int wrstride,
                                              OutT* __restrict__ out, int outCtot, int orow0)
{
    __shared__ __align__(16) short As[48 * 40];
    __shared__ __align__(16) short Bs[128 * 40];

    const int t  = threadIdx.x;
    const int p0 = blockIdx.x * 128;
    const int bm = blockIdx.y;
    const int b  = blockIdx.z;

    const int l   = t & 63;
    const int wv  = t >> 6;   // wave id 0..3 -> n slice
    const int l15 = l & 15;
    const int q   = l >> 4;   // quad 0..3

    f32x4 acc[3][2];
#pragma unroll
    for (int mt = 0; mt < 3; ++mt)
#pragma unroll
        for (int nt = 0; nt < 2; ++nt) acc[mt][nt] = (f32x4){0.f, 0.f, 0.f, 0.f};

    const int c4 = t >> 4;   // 0..15 : pixel group (8 pixels)
    const int rp = t & 15;   // 0..15 : k row pair
    const int KB = K - Ksplit;

    for (int k0 = 0; k0 < K; k0 += 32) {
        const SrcT* sb;
        if (k0 < Ksplit) sb = srcA + ((size_t)b * Ksplit + k0) * NPIX;
        else             sb = srcB + ((size_t)b * KB + (k0 - Ksplit)) * NPIX;
        __syncthreads();
        // ---- stage A: 48 rows x 32 k of weights (fp32 -> bf16)
#pragma unroll
        for (int i = 0; i < 3; ++i) {
            int idx = t + i * 256;            // 0..767
            int row = idx >> 4, kq = idx & 15;
            const float* wr = w + (size_t)(wrow0 + bm * wrstride + row) * K + k0 + kq * 2;
            float2 wv2 = *(const float2*)wr;
            *(unsigned*)&As[row * 40 + kq * 2] = pack2f(wv2.x, wv2.y);
        }
        // ---- stage B: 32 k x 128 n of src, transposed to Bs[n][k]
        const SrcT* r0 = sb + (size_t)(2 * rp) * NPIX + p0 + c4 * 8;
        const SrcT* r1 = r0 + NPIX;
        if constexpr (sizeof(SrcT) == 4) {
            float4 a0 = *(const float4*)r0, a1 = *(const float4*)(r0 + 4);
            float4 b0 = *(const float4*)r1, b1 = *(const float4*)(r1 + 4);
            float ra[8] = {a0.x, a0.y, a0.z, a0.w, a1.x, a1.y, a1.z, a1.w};
            float rb[8] = {b0.x, b0.y, b0.z, b0.w, b1.x, b1.y, b1.z, b1.w};
#pragma unroll
            for (int j = 0; j < 8; ++j)
                *(unsigned*)&Bs[(c4 * 8 + j) * 40 + rp * 2] = pack2f(ra[j], rb[j]);
        } else {
            bf16x8 a = *(const bf16x8*)(const void*)r0;
            bf16x8 bb = *(const bf16x8*)(const void*)r1;
#pragma unroll
            for (int j = 0; j < 8; ++j) {
                unsigned lo = (unsigned short)a[j];
                unsigned hi = (unsigned short)bb[j];
                *(unsigned*)&Bs[(c4 * 8 + j) * 40 + rp * 2] = lo | (hi << 16);
            }
        }
        __syncthreads();
        // ---- fragments + MFMA
        bf16x8 af[3], bfr[2];
#pragma unroll
        for (int mt = 0; mt < 3; ++mt)
            af[mt] = *(const bf16x8*)&As[(mt * 16 + l15) * 40 + q * 8];
#pragma unroll
        for (int nt = 0; nt < 2; ++nt)
            bfr[nt] = *(const bf16x8*)&Bs[(wv * 32 + nt * 16 + l15) * 40 + q * 8];
#pragma unroll
        for (int mt = 0; mt < 3; ++mt)
#pragma unroll
            for (int nt = 0; nt < 2; ++nt)
                acc[mt][nt] = __builtin_amdgcn_mfma_f32_16x16x32_bf16(
                    af[mt], bfr[nt], acc[mt][nt], 0, 0, 0);
    }
    // ---- epilogue: C/D layout col=lane&15, row=quad*4+reg (m89-verified)
#pragma unroll
    for (int mt = 0; mt < 3; ++mt)
#pragma unroll
        for (int nt = 0; nt < 2; ++nt)
#pragma unroll
            for (int r = 0; r < 4; ++r) {
                int row = orow0 + bm * 48 + mt * 16 + q * 4 + r;
                int col = p0 + wv * 32 + nt * 16 + l15;
                out[((size_t)b * outCtot + row) * NPIX + col] = stv<OutT>(acc[mt][nt][r]);
            }
}

// ---------------------------------------------------------------------------
// Depthwise 3x3, pad=1, optional exact GELU. Weight channel for launch channel c:
//   wch = wbase + (c/48)*wgstride + (c%48)   (bs: wbase=0,wgs=48 -> wch=c;
//                                             qkv head h: wbase=h*48, wgs=384)
// grid: (64, C, B)
// ---------------------------------------------------------------------------
template <typename InT, typename OutT>
__global__ __launch_bounds__(256) void dw3x3(const InT* __restrict__ in,
                                             const float* __restrict__ w,
                                             OutT* __restrict__ out,
                                             int Ctot, int wbase, int wgstride,
                                             int applyGelu)
{
    const int tid = threadIdx.x;
    const int p = blockIdx.x * 256 + tid;
    const int c = blockIdx.y;
    const int b = blockIdx.z;
    const int y = p >> 7;
    const int xx = p & 127;

    const int g = c / 48;
    const int wch = wbase + g * wgstride + (c - g * 48);

    const InT* ib = in + ((size_t)b * Ctot + c) * NPIX;
    float wv[9];
#pragma unroll
    for (int i = 0; i < 9; ++i) wv[i] = w[wch * 9 + i];

    float acc = 0.f;
#pragma unroll
    for (int dy = -1; dy <= 1; ++dy) {
        int yy = y + dy;
        if (yy < 0 || yy > 127) continue;
#pragma unroll
        for (int dx = -1; dx <= 1; ++dx) {
            int xc = xx + dx;
            if (xc < 0 || xc > 127) continue;
            acc += ldv(ib[yy * 128 + xc]) * wv[(dy + 1) * 3 + (dx + 1)];
        }
    }
    if (applyGelu) acc = 0.5f * acc * (1.0f + erff(acc * 0.70710678118654752f));
    out[((size_t)b * Ctot + c) * NPIX + p] = stv<OutT>(acc);
}

// ---------------------------------------------------------------------------
// Per-head inv-L2-norm factors over qkv_head buffer (144 ch: q=0..47 k=48..95).
// grid: 2*4*48 = 384 blocks. inv layout: [which(2)][b(4)][c(48)].
// ---------------------------------------------------------------------------
__global__ __launch_bounds__(256) void l2norm_head(const bf16* __restrict__ qkvh,
                                                   float* __restrict__ inv)
{
    const int id = blockIdx.x;
    const int which = id / 192;
    const int rem = id - which * 192;
    const int b = rem / 48, c = rem - b * 48;
    const bf16* base = qkvh + ((size_t)b * 144 + which * 48 + c) * NPIX;

    float s = 0.f;
    for (int p = threadIdx.x; p < NPIX; p += 256) {
        float v = ldv(base[p]);
        s += v * v;
    }
#pragma unroll
    for (int off = 32; off; off >>= 1) s += __shfl_down(s, off, 64);
    __shared__ float partial[4];
    if ((threadIdx.x & 63) == 0) partial[threadIdx.x >> 6] = s;
    __syncthreads();
    if (threadIdx.x == 0) {
        float t = partial[0] + partial[1] + partial[2] + partial[3];
        inv[id] = 1.0f / fmaxf(sqrtf(t), 1e-12f);
    }
}

// ---------------------------------------------------------------------------
// Per-head attention logit partials, pixel-sliced for occupancy:
//   logits_p[slice, b, i, j] = scale*invq[i]*invk[j]*sum_{p in slice} q_i[p]k_j[p]
// grid: (48, 4, 8). softmax_av sums the 8 slices.
// ---------------------------------------------------------------------------
__global__ __launch_bounds__(256) void qk_logits_head(const bf16* __restrict__ qkvh,
                                                      const float* __restrict__ inv,
                                                      float* __restrict__ logits_p)
{
    const int i = blockIdx.x;
    const int b = blockIdx.y;
    const int slice = blockIdx.z;
    const int tid = threadIdx.x;

    const bf16* qrow  = qkvh + ((size_t)b * 144 + i) * NPIX;
    const bf16* kbase = qkvh + ((size_t)b * 144 + 48) * NPIX;

    float acc[48];
#pragma unroll
    for (int j = 0; j < 48; ++j) acc[j] = 0.f;

    const int pend = slice * 2048 + 2048;
    for (int p = slice * 2048 + tid; p < pend; p += 256) {
        float qv = ldv(qrow[p]);
#pragma unroll
        for (int j = 0; j < 48; ++j)
            acc[j] += qv * ldv(kbase[(size_t)j * NPIX + p]);
    }

    __shared__ float red[4][48];
    const int lane = tid & 63, wave = tid >> 6;
#pragma unroll
    for (int j = 0; j < 48; ++j) {
        float s = acc[j];
#pragma unroll
        for (int off = 32; off; off >>= 1) s += __shfl_down(s, off, 64);
        if (lane == 0) red[wave][j] = s;
    }
    __syncthreads();
    if (tid < 48) {
        float s = red[0][tid] + red[1][tid] + red[2][tid] + red[3][tid];
        float qn = inv[b * 48 + i];
        float kn = inv[192 + b * 48 + tid];
        logits_p[((size_t)slice * 192 + b * 48 + i) * 48 + tid] =
            s * 0.14433756729740643f * qn * kn;
    }
}

// ---------------------------------------------------------------------------
// Per-head softmax (over 8 summed partials) + AV into attn channels h*48+i.
// grid: (64, 48, 4)
// ---------------------------------------------------------------------------
__global__ __launch_bounds__(256) void softmax_av_head(const float* __restrict__ logits_p,
                                                       const bf16* __restrict__ qkvh,
                                                       bf16* __restrict__ attn, int h)
{
    const int tid = threadIdx.x;
    const int p = blockIdx.x * 256 + tid;
    const int i = blockIdx.y;
    const int b = blockIdx.z;

    __shared__ float arow[48];
    if (tid < 64) {
        float l = -1e30f;
        if (tid < 48) {
            l = 0.f;
#pragma unroll
            for (int s = 0; s < 8; ++s)
                l += logits_p[((size_t)s * 192 + b * 48 + i) * 48 + tid];
        }
        float m = l;
#pragma unroll
        for (int off = 32; off; off >>= 1) m = fmaxf(m, __shfl_xor(m, off, 64));
        float e = (tid < 48) ? expf(l - m) : 0.f;
        float s = e;
#pragma unroll
        for (int off = 32; off; off >>= 1) s += __shfl_xor(s, off, 64);
        if (tid < 48) arow[tid] = e / s;
    }
    __syncthreads();

    const bf16* vbase = qkvh + ((size_t)b * 144 + 96) * NPIX + p;
    float acc = 0.f;
#pragma unroll
    for (int j = 0; j < 48; ++j) acc += arow[j] * ldv(vbase[(size_t)j * NPIX]);
    attn[((size_t)b * 384 + h * 48 + i) * NPIX + p] = stv<bf16>(acc);
}

// ---------------------------------------------------------------------------
extern "C" void kernel_launch(void* const* d_in, const int* in_sizes, int n_in,
                              void* d_out, int out_size, void* d_ws, size_t ws_size,
                              hipStream_t stream) {
    const float* x       = (const float*)d_in[0];
    const float* w_qkv   = (const float*)d_in[1];
    const float* w_dw    = (const float*)d_in[2];
    const float* w_proj  = (const float*)d_in[3];
    const float* w_bs_pw = (const float*)d_in[4];
    const float* w_bs_dw = (const float*)d_in[5];
    float* out = (float*)d_out;

    // workspace layout — peak ≈138.7 MB (138.5 proven safe in R2/R3)
    char* ws = (char*)d_ws;
    bf16* y_gelu   = (bf16*)ws;                         //  50,331,648 B
    bf16* attn     = (bf16*)(ws + 50331648);            //  50,331,648 B
    bf16* qkvp     = (bf16*)(ws + 100663296);           //  18,874,368 B (head pw out)
    bf16* qkvd     = (bf16*)(ws + 119537664);           //  18,874,368 B (head dw out)
    float* inv     = (float*)(ws + 138412032);          //  1,536 B
    float* logitsp = (float*)(ws + 138416128);          //  294,912 B (8 slices)
    bf16* y1 = (bf16*)d_out;  // bs_pw bf16 output lives in d_out space until proj

    dim3 blk(256);
    // BSConv branch: pw (MFMA, bf16 out into d_out space) -> dw+GELU
    gemm48<float, bf16><<<dim3(128, 8, 4), blk, 0, stream>>>(
        x, x, 384, w_bs_pw, 384, 0, 48, y1, 384, 0);
    dw3x3<bf16, bf16><<<dim3(64, 384, 4), blk, 0, stream>>>(
        y1, w_bs_dw, y_gelu, 384, 0, 48, 1);

    // attention path, one head (48 q + 48 k + 48 v channels) at a time
    for (int h = 0; h < 8; ++h) {
        gemm48<float, bf16><<<dim3(128, 3, 4), blk, 0, stream>>>(
            x, x, 384, w_qkv, 384, h * 48, 384, qkvp, 144, 0);
        dw3x3<bf16, bf16><<<dim3(64, 144, 4), blk, 0, stream>>>(
            qkvp, w_dw, qkvd, 144, h * 48, 384, 0);
        l2norm_head<<<dim3(384), blk, 0, stream>>>(qkvd, inv);
        qk_logits_head<<<dim3(48, 4, 8), blk, 0, stream>>>(qkvd, inv, logitsp);
        softmax_av_head<<<dim3(64, 48, 4), blk, 0, stream>>>(logitsp, qkvd, attn, h);
    }

    // projection over (attn ++ y_gelu) -> fp32 out  (K-split replaces concat)
    gemm48<bf16, float><<<dim3(128, 8, 4), blk, 0, stream>>>(
        attn, y_gelu, 384, w_proj, 768, 0, 48, out, 384, 0);
}

// Round 5
// 1055.663 us; speedup vs baseline: 5.2780x; 1.8868x over previous
//
#include <hip/hip_runtime.h>
#include <hip/hip_bf16.h>
#include <math.h>

typedef __hip_bfloat16 bf16;
typedef short bf16x8 __attribute__((ext_vector_type(8)));
typedef float f32x4 __attribute__((ext_vector_type(4)));

#define NPIX 16384  // 128*128 spatial per channel

static __device__ __forceinline__ float ldv(float v) { return v; }
static __device__ __forceinline__ float ldv(bf16 v) { return __bfloat162float(v); }
static __device__ __forceinline__ float lds16(short s) {
    union { short s_; bf16 h; } u; u.s_ = s; return __bfloat162float(u.h);
}
template <typename T> static __device__ __forceinline__ T stv(float v);
template <> __device__ __forceinline__ float stv<float>(float v) { return v; }
template <> __device__ __forceinline__ bf16 stv<bf16>(float v) { return __float2bfloat16(v); }
static __device__ __forceinline__ short stv16(float v) {
    union { short s_; bf16 h; } u; u.h = __float2bfloat16(v); return u.s_;
}

static __device__ __forceinline__ unsigned pack2f(float a, float b) {
    union { bf16 h; unsigned short u; } ua, ub;
    ua.h = __float2bfloat16(a); ub.h = __float2bfloat16(b);
    return (unsigned)ua.u | ((unsigned)ub.u << 16);
}
static __device__ __forceinline__ unsigned packbb(unsigned short lo, unsigned short hi) {
    return (unsigned)lo | ((unsigned)hi << 16);
}

template <typename SrcT>
static __device__ __forceinline__ const SrcT* maprow(const SrcT* A, const SrcT* B, int k,
    int Ksplit, int agrp, int ags, int abss, int bgrp, int bgs, int bbs, int b)
{
    if (k < Ksplit) return A + (size_t)((k / agrp) * ags + b * abss + (k % agrp)) * NPIX;
    k -= Ksplit;
    return B + (size_t)((k / bgrp) * bgs + b * bbs + (k % bgrp)) * NPIX;
}

// ---------------------------------------------------------------------------
// Pipelined MFMA pointwise GEMM (BM=48, BN=128, BK=32, dbuf LDS, 1 barrier/step).
//   weight row   = wrow0 + (bm%wMod)*wsA + (bm/wMod)*wsB + r
//   src row (k)  = (k/agrp)*ags + b*abss + k%agrp  (srcA; srcB analog after Ksplit)
//   out row      = orow0 + (bm%oMod)*osA + (bm/oMod)*osB + b*obS + r
// grid: (Mblocks, 128, B)
// ---------------------------------------------------------------------------
template <typename SrcT, typename OutT>
__global__ __launch_bounds__(256) void gemm48(
    const SrcT* __restrict__ srcA, const SrcT* __restrict__ srcB, int Ksplit, int K,
    int agrp, int ags, int abss, int bgrp, int bgs, int bbs,
    const float* __restrict__ w, int wMod, int wsA, int wsB, int wrow0,
    OutT* __restrict__ out, int oMod, int osA, int osB, int obS, int orow0)
{
    __shared__ __align__(16) short As[2][48 * 40];
    __shared__ __align__(16) short Bs[2][128 * 40];

    const int t  = threadIdx.x;
    const int bm = blockIdx.x;
    const int p0 = blockIdx.y * 128;
    const int b  = blockIdx.z;

    const int l = t & 63, wvid = t >> 6, l15 = l & 15, q = l >> 4;
    const int c4 = t >> 4, rp = t & 15;

    const int wbase = wrow0 + (bm % wMod) * wsA + (bm / wMod) * wsB;

    f32x4 acc[3][2];
#pragma unroll
    for (int mt = 0; mt < 3; ++mt)
#pragma unroll
        for (int nt = 0; nt < 2; ++nt) acc[mt][nt] = (f32x4){0.f, 0.f, 0.f, 0.f};

    float aw[6];
    float fb[16];
    bf16x8 hA, hB;

    auto LOADA = [&](int k0) {
#pragma unroll
        for (int i = 0; i < 3; ++i) {
            int idx = t + i * 256, row = idx >> 4, kq = idx & 15;
            float2 v = *(const float2*)(w + (size_t)(wbase + row) * K + k0 + kq * 2);
            aw[2 * i] = v.x; aw[2 * i + 1] = v.y;
        }
    };
    auto STOREA = [&](int buf) {
#pragma unroll
        for (int i = 0; i < 3; ++i) {
            int idx = t + i * 256, row = idx >> 4, kq = idx & 15;
            *(unsigned*)&As[buf][row * 40 + kq * 2] = pack2f(aw[2 * i], aw[2 * i + 1]);
        }
    };
    auto LOADB = [&](int k0) {
        const SrcT* r0 = maprow(srcA, srcB, k0 + 2 * rp,     Ksplit, agrp, ags, abss, bgrp, bgs, bbs, b) + p0 + c4 * 8;
        const SrcT* r1 = maprow(srcA, srcB, k0 + 2 * rp + 1, Ksplit, agrp, ags, abss, bgrp, bgs, bbs, b) + p0 + c4 * 8;
        if constexpr (sizeof(SrcT) == 4) {
            float4 a0 = *(const float4*)r0, a1 = *(const float4*)(r0 + 4);
            float4 b0 = *(const float4*)r1, b1 = *(const float4*)(r1 + 4);
            fb[0] = a0.x; fb[1] = a0.y; fb[2] = a0.z; fb[3] = a0.w;
            fb[4] = a1.x; fb[5] = a1.y; fb[6] = a1.z; fb[7] = a1.w;
            fb[8] = b0.x; fb[9] = b0.y; fb[10] = b0.z; fb[11] = b0.w;
            fb[12] = b1.x; fb[13] = b1.y; fb[14] = b1.z; fb[15] = b1.w;
        } else {
            hA = *(const bf16x8*)(const void*)r0;
            hB = *(const bf16x8*)(const void*)r1;
        }
    };
    auto STOREB = [&](int buf) {
#pragma unroll
        for (int j = 0; j < 8; ++j) {
            unsigned d;
            if constexpr (sizeof(SrcT) == 4) d = pack2f(fb[j], fb[8 + j]);
            else d = packbb((unsigned short)hA[j], (unsigned short)hB[j]);
            *(unsigned*)&Bs[buf][(c4 * 8 + j) * 40 + rp * 2] = d;
        }
    };

    LOADA(0); LOADB(0);
    STOREA(0); STOREB(0);
    const int S = K / 32;
    for (int s = 0; s < S; ++s) {
        const int cur = s & 1;
        __syncthreads();
        if (s + 1 < S) { LOADA((s + 1) * 32); LOADB((s + 1) * 32); }
        bf16x8 af[3], bfr[2];
#pragma unroll
        for (int mt = 0; mt < 3; ++mt)
            af[mt] = *(const bf16x8*)&As[cur][(mt * 16 + l15) * 40 + q * 8];
#pragma unroll
        for (int nt = 0; nt < 2; ++nt)
            bfr[nt] = *(const bf16x8*)&Bs[cur][(wvid * 32 + nt * 16 + l15) * 40 + q * 8];
#pragma unroll
        for (int mt = 0; mt < 3; ++mt)
#pragma unroll
            for (int nt = 0; nt < 2; ++nt)
                acc[mt][nt] = __builtin_amdgcn_mfma_f32_16x16x32_bf16(
                    af[mt], bfr[nt], acc[mt][nt], 0, 0, 0);
        if (s + 1 < S) { STOREA(1 - cur); STOREB(1 - cur); }
    }

    const int obase = orow0 + (bm % oMod) * osA + (bm / oMod) * osB + b * obS;
#pragma unroll
    for (int mt = 0; mt < 3; ++mt)
#pragma unroll
        for (int nt = 0; nt < 2; ++nt)
#pragma unroll
            for (int r = 0; r < 4; ++r) {
                int row = obase + mt * 16 + q * 4 + r;
                int col = p0 + wvid * 32 + nt * 16 + l15;
                out[(size_t)row * NPIX + col] = stv<OutT>(acc[mt][nt][r]);
            }
}

// ---------------------------------------------------------------------------
// Vectorized depthwise 3x3 (+optional exact GELU). 8 px/thread, b128 loads.
//   isQkv: c -> h=c/144, r=c%144: inRow=h*ig+b*inB+r, wch=(r/48)*384+h*48+whofs+r%48,
//          outRow=h*og+b*outB+r+obase.   else: inRow=b*inB+c, wch=c, outRow=b*outB+c.
// grid: (8, C, B)
// ---------------------------------------------------------------------------
__global__ __launch_bounds__(256) void dw3x3v(
    const bf16* __restrict__ in, const float* __restrict__ w, bf16* __restrict__ out,
    int isQkv, int whofs, int inB, int ig, int outB, int og, int obase, int applyGelu)
{
    const int t = threadIdx.x;
    const int g = blockIdx.x * 256 + t;   // 0..2047 groups of 8 px
    const int c = blockIdx.y;
    const int b = blockIdx.z;
    const int y = g >> 4;
    const int x0 = (g & 15) * 8;

    int inRow, wch, outRow;
    if (isQkv) {
        int h = c / 144, r = c - h * 144;
        inRow  = h * ig + b * inB + r;
        wch    = (r / 48) * 384 + h * 48 + whofs + (r % 48);
        outRow = h * og + b * outB + r + obase;
    } else {
        inRow = b * inB + c; wch = c; outRow = b * outB + c;
    }

    const bf16* ib = in + (size_t)inRow * NPIX;
    float wv[9];
#pragma unroll
    for (int i = 0; i < 9; ++i) wv[i] = w[wch * 9 + i];

    float vv[3][10];
#pragma unroll
    for (int dy = 0; dy < 3; ++dy) {
        int yy = y + dy - 1;
        if (yy < 0 || yy > 127) {
#pragma unroll
            for (int j = 0; j < 10; ++j) vv[dy][j] = 0.f;
        } else {
            const bf16* rb = ib + yy * 128;
            bf16x8 m = *(const bf16x8*)(const void*)(rb + x0);
#pragma unroll
            for (int j = 0; j < 8; ++j) vv[dy][j + 1] = lds16(m[j]);
            vv[dy][0] = (x0 > 0)   ? ldv(rb[x0 - 1]) : 0.f;
            vv[dy][9] = (x0 < 120) ? ldv(rb[x0 + 8]) : 0.f;
        }
    }
    bf16x8 res;
#pragma unroll
    for (int j = 0; j < 8; ++j) {
        float a = 0.f;
#pragma unroll
        for (int dy = 0; dy < 3; ++dy)
#pragma unroll
            for (int dx = 0; dx < 3; ++dx)
                a += wv[dy * 3 + dx] * vv[dy][j + dx];
        if (applyGelu) a = 0.5f * a * (1.0f + erff(a * 0.70710678118654752f));
        res[j] = stv16(a);
    }
    *(bf16x8*)(void*)(out + (size_t)outRow * NPIX + y * 128 + x0) = res;
}

// ---------------------------------------------------------------------------
// inv-L2-norm, vectorized. grid: 2*NBH*48 blocks over qkvd [bh][144][p].
// inv layout: [which][bh][c].
// ---------------------------------------------------------------------------
__global__ __launch_bounds__(256) void l2norm_v(const bf16* __restrict__ qkvd,
                                                float* __restrict__ inv, int NBH)
{
    const int id = blockIdx.x;
    const int which = id / (NBH * 48);
    const int rem = id - which * NBH * 48;
    const int bh = rem / 48, c = rem - bh * 48;
    const bf16* base = qkvd + (size_t)(bh * 144 + which * 48 + c) * NPIX;

    float s = 0.f;
#pragma unroll
    for (int it = 0; it < 8; ++it) {
        bf16x8 v = *(const bf16x8*)(const void*)(base + ((size_t)threadIdx.x + it * 256) * 8);
#pragma unroll
        for (int j = 0; j < 8; ++j) { float f = lds16(v[j]); s += f * f; }
    }
#pragma unroll
    for (int off = 32; off; off >>= 1) s += __shfl_down(s, off, 64);
    __shared__ float partial[4];
    if ((threadIdx.x & 63) == 0) partial[threadIdx.x >> 6] = s;
    __syncthreads();
    if (threadIdx.x == 0) {
        float tt = partial[0] + partial[1] + partial[2] + partial[3];
        inv[(which * NBH + bh) * 48 + c] = 1.0f / fmaxf(sqrtf(tt), 1e-12f);
    }
}

// ---------------------------------------------------------------------------
// QK^T logits partials via MFMA, direct-from-global fragments (both operands
// p-contiguous -> no LDS, no transpose). Each wave = one k-slice of pxs pixels.
// lp[slice][bh][i*48+j] = raw dot partial. grid: (NBH, NSL/4), block 256.
// ---------------------------------------------------------------------------
__global__ __launch_bounds__(256) void qk_mfma(const bf16* __restrict__ qkvd,
                                               float* __restrict__ lp, int NBH, int pxs)
{
    const int bh = blockIdx.x;
    const int wvid = threadIdx.x >> 6;
    const int slice = blockIdx.y * 4 + wvid;
    const int l = threadIdx.x & 63, l15 = l & 15, q = l >> 4;

    const bf16* qb = qkvd + (size_t)(bh * 144) * NPIX;
    const bf16* kb = qb + (size_t)48 * NPIX;

    f32x4 acc[3][3];
#pragma unroll
    for (int mt = 0; mt < 3; ++mt)
#pragma unroll
        for (int nt = 0; nt < 3; ++nt) acc[mt][nt] = (f32x4){0.f, 0.f, 0.f, 0.f};

    const int pbeg = slice * pxs;
    for (int kk = 0; kk < pxs; kk += 32) {
        const int pc = pbeg + kk + q * 8;
        bf16x8 af[3], bfv[3];
#pragma unroll
        for (int mt = 0; mt < 3; ++mt)
            af[mt] = *(const bf16x8*)(const void*)(qb + (size_t)(mt * 16 + l15) * NPIX + pc);
#pragma unroll
        for (int nt = 0; nt < 3; ++nt)
            bfv[nt] = *(const bf16x8*)(const void*)(kb + (size_t)(nt * 16 + l15) * NPIX + pc);
#pragma unroll
        for (int mt = 0; mt < 3; ++mt)
#pragma unroll
            for (int nt = 0; nt < 3; ++nt)
                acc[mt][nt] = __builtin_amdgcn_mfma_f32_16x16x32_bf16(
                    af[mt], bfv[nt], acc[mt][nt], 0, 0, 0);
    }
    float* o = lp + ((size_t)slice * NBH + bh) * 2304;
#pragma unroll
    for (int mt = 0; mt < 3; ++mt)
#pragma unroll
        for (int nt = 0; nt < 3; ++nt)
#pragma unroll
            for (int r = 0; r < 4; ++r)
                o[(mt * 16 + q * 4 + r) * 48 + nt * 16 + l15] = acc[mt][nt][r];
}

// ---------------------------------------------------------------------------
// Sum NSL slice-partials, apply scale*invq*invk, row-softmax, emit bf16
// attention weights a_bf[bh][48][64] (zero-padded K to 64). grid: (NBH)
// ---------------------------------------------------------------------------
__global__ __launch_bounds__(256) void softmax48(const float* __restrict__ lp,
                                                 const float* __restrict__ inv,
                                                 bf16* __restrict__ a_bf, int NBH, int NSL)
{
    const int bh = blockIdx.x, t = threadIdx.x;
    __shared__ float L[2304];
    for (int e = t; e < 2304; e += 256) {
        float s = 0.f;
        for (int sl = 0; sl < NSL; ++sl) s += lp[((size_t)sl * NBH + bh) * 2304 + e];
        int i = e / 48, j = e - i * 48;
        L[e] = s * 0.14433756729740643f * inv[bh * 48 + i] * inv[(NBH + bh) * 48 + j];
    }
    __syncthreads();
    if (t < 48) {
        float m = -1e30f;
#pragma unroll
        for (int j = 0; j < 48; ++j) m = fmaxf(m, L[t * 48 + j]);
        float e_[48]; float ssum = 0.f;
#pragma unroll
        for (int j = 0; j < 48; ++j) { e_[j] = expf(L[t * 48 + j] - m); ssum += e_[j]; }
        float r = 1.f / ssum;
        bf16* ab = a_bf + (size_t)bh * 3072 + t * 64;
#pragma unroll
        for (int j = 0; j < 48; ++j) ab[j] = stv<bf16>(e_[j] * r);
#pragma unroll
        for (int j = 48; j < 64; ++j) ab[j] = stv<bf16>(0.f);
    }
}

// ---------------------------------------------------------------------------
// AV via MFMA: out[row(i)][p] = sum_j a_bf[bh][i][j] * v[j][p].
// A = a_bf (direct global frags, K=64 zero-padded); B = v transpose-staged.
// out row = obase + bh*oS + i. grid: (128, NBH)
// ---------------------------------------------------------------------------
__global__ __launch_bounds__(256) void av_mfma(const bf16* __restrict__ a_bf,
                                               const bf16* __restrict__ qkvd,
                                               bf16* __restrict__ out, int obase, int oS)
{
    __shared__ __align__(16) short Bs[128 * 72];
    const int t = threadIdx.x;
    const int px0 = blockIdx.x * 128;
    const int bh = blockIdx.y;
    const int l = t & 63, wvid = t >> 6, l15 = l & 15, q = l >> 4;
    const int c4 = t >> 4, rp = t & 15;

    const bf16* ab = a_bf + (size_t)bh * 3072;
    bf16x8 af[3][2];
#pragma unroll
    for (int mt = 0; mt < 3; ++mt)
#pragma unroll
        for (int kq = 0; kq < 2; ++kq)
            af[mt][kq] = *(const bf16x8*)(const void*)(ab + (mt * 16 + l15) * 64 + kq * 32 + q * 8);

    const bf16* vb = qkvd + (size_t)(bh * 144 + 96) * NPIX;
    bf16x8 vr[4];
#pragma unroll
    for (int jj = 0; jj < 4; ++jj) {
        int j = rp * 4 + jj; int jc = j < 48 ? j : 47;   // pad rows killed by zero A
        vr[jj] = *(const bf16x8*)(const void*)(vb + (size_t)jc * NPIX + px0 + c4 * 8);
    }
#pragma unroll
    for (int j = 0; j < 8; ++j) {
        *(unsigned*)&Bs[(c4 * 8 + j) * 72 + rp * 4]     = packbb((unsigned short)vr[0][j], (unsigned short)vr[1][j]);
        *(unsigned*)&Bs[(c4 * 8 + j) * 72 + rp * 4 + 2] = packbb((unsigned short)vr[2][j], (unsigned short)vr[3][j]);
    }
    __syncthreads();

    f32x4 acc[3][2];
#pragma unroll
    for (int mt = 0; mt < 3; ++mt)
#pragma unroll
        for (int nt = 0; nt < 2; ++nt) acc[mt][nt] = (f32x4){0.f, 0.f, 0.f, 0.f};

    bf16x8 bfv[2][2];
#pragma unroll
    for (int nt = 0; nt < 2; ++nt)
#pragma unroll
        for (int kq = 0; kq < 2; ++kq)
            bfv[nt][kq] = *(const bf16x8*)&Bs[(wvid * 32 + nt * 16 + l15) * 72 + kq * 32 + q * 8];
#pragma unroll
    for (int kq = 0; kq < 2; ++kq)
#pragma unroll
        for (int mt = 0; mt < 3; ++mt)
#pragma unroll
            for (int nt = 0; nt < 2; ++nt)
                acc[mt][nt] = __builtin_amdgcn_mfma_f32_16x16x32_bf16(
                    af[mt][kq], bfv[nt][kq], acc[mt][nt], 0, 0, 0);
#pragma unroll
    for (int mt = 0; mt < 3; ++mt)
#pragma unroll
        for (int nt = 0; nt < 2; ++nt)
#pragma unroll
            for (int r = 0; r < 4; ++r) {
                int row = obase + bh * oS + mt * 16 + q * 4 + r;
                int col = px0 + wvid * 32 + nt * 16 + l15;
                out[(size_t)row * NPIX + col] = stv<bf16>(acc[mt][nt][r]);
            }
}

// ---------------------------------------------------------------------------
extern "C" void kernel_launch(void* const* d_in, const int* in_sizes, int n_in,
                              void* d_out, int out_size, void* d_ws, size_t ws_size,
                              hipStream_t stream) {
    const float* x       = (const float*)d_in[0];
    const float* w_qkv   = (const float*)d_in[1];
    const float* w_dw    = (const float*)d_in[2];
    const float* w_proj  = (const float*)d_in[3];
    const float* w_bs_pw = (const float*)d_in[4];
    const float* w_bs_dw = (const float*)d_in[5];
    float* out = (float*)d_out;
    bf16* y1 = (bf16*)d_out;  // bs_pw bf16 output lives in d_out space until proj

    const size_t SZQ = 150994944ull;  // 8h*4b*144*16384*2
    const size_t SZH = 18874368ull;   // 4b*144*16384*2
    const size_t SZY = 50331648ull;   // 4b*384*16384*2
    char* ws = (char*)d_ws;
    dim3 blk(256);

    if (ws_size >= 371404800ull) {
        // ---------- FULL: all heads batched, 9 launches ----------
        bf16* qkvp = (bf16*)ws;
        bf16* qkvd = (bf16*)(ws + SZQ);
        bf16* yg   = (bf16*)(ws + 2 * SZQ);
        float* lp  = (float*)(ws + 2 * SZQ + SZY);
        bf16* abf  = (bf16*)(ws + 2 * SZQ + SZY + 18874368ull);
        float* inv = (float*)(ws + 2 * SZQ + SZY + 18874368ull + 196608ull);

        gemm48<float, bf16><<<dim3(24, 128, 4), blk, 0, stream>>>(
            x, x, 384, 384, 384, 0, 384, 384, 0, 384,
            w_qkv, 3, 384, 48, 0, qkvp, 3, 48, 576, 144, 0);
        dw3x3v<<<dim3(8, 1152, 4), blk, 0, stream>>>(
            qkvp, w_dw, qkvd, 1, 0, 144, 576, 144, 576, 0, 0);
        l2norm_v<<<dim3(2 * 32 * 48), blk, 0, stream>>>(qkvd, inv, 32);
        qk_mfma<<<dim3(32, 16), blk, 0, stream>>>(qkvd, lp, 32, 256);
        softmax48<<<dim3(32), blk, 0, stream>>>(lp, inv, abf, 32, 64);
        gemm48<float, bf16><<<dim3(8, 128, 4), blk, 0, stream>>>(
            x, x, 384, 384, 384, 0, 384, 384, 0, 384,
            w_bs_pw, 1, 0, 48, 0, y1, 1, 0, 48, 384, 0);
        dw3x3v<<<dim3(8, 384, 4), blk, 0, stream>>>(
            y1, w_bs_dw, yg, 0, 0, 384, 0, 384, 0, 0, 1);
        av_mfma<<<dim3(128, 32), blk, 0, stream>>>(abf, qkvd, qkvd, 0, 144);
        gemm48<bf16, float><<<dim3(8, 128, 4), blk, 0, stream>>>(
            qkvd, yg, 384, 768, 48, 576, 144, 384, 0, 384,
            w_proj, 1, 0, 48, 0, out, 1, 0, 48, 384, 0);
    } else if (ws_size >= 239284224ull) {
        // ---------- LITE: per-head pw+dw, rest batched ----------
        bf16* qkvd = (bf16*)ws;
        bf16* qph  = (bf16*)(ws + SZQ);
        bf16* yg   = (bf16*)(ws + SZQ + SZH);
        float* lp  = (float*)(ws + SZQ + SZH + SZY);
        bf16* abf  = (bf16*)(ws + SZQ + SZH + SZY + 18874368ull);
        float* inv = (float*)(ws + SZQ + SZH + SZY + 18874368ull + 196608ull);

        for (int h = 0; h < 8; ++h) {
            gemm48<float, bf16><<<dim3(3, 128, 4), blk, 0, stream>>>(
                x, x, 384, 384, 384, 0, 384, 384, 0, 384,
                w_qkv, 3, 384, 48, h * 48, qph, 3, 48, 0, 144, 0);
            dw3x3v<<<dim3(8, 144, 4), blk, 0, stream>>>(
                qph, w_dw, qkvd, 1, h * 48, 144, 0, 144, 0, h * 576, 0);
        }
        l2norm_v<<<dim3(2 * 32 * 48), blk, 0, stream>>>(qkvd, inv, 32);
        qk_mfma<<<dim3(32, 16), blk, 0, stream>>>(qkvd, lp, 32, 256);
        softmax48<<<dim3(32), blk, 0, stream>>>(lp, inv, abf, 32, 64);
        gemm48<float, bf16><<<dim3(8, 128, 4), blk, 0, stream>>>(
            x, x, 384, 384, 384, 0, 384, 384, 0, 384,
            w_bs_pw, 1, 0, 48, 0, y1, 1, 0, 48, 384, 0);
        dw3x3v<<<dim3(8, 384, 4), blk, 0, stream>>>(
            y1, w_bs_dw, yg, 0, 0, 384, 0, 384, 0, 0, 1);
        av_mfma<<<dim3(128, 32), blk, 0, stream>>>(abf, qkvd, qkvd, 0, 144);
        gemm48<bf16, float><<<dim3(8, 128, 4), blk, 0, stream>>>(
            qkvd, yg, 384, 768, 48, 576, 144, 384, 0, 384,
            w_proj, 1, 0, 48, 0, out, 1, 0, 48, 384, 0);
    } else {
        // ---------- ULTRA: fully per-head (~139.6 MB) ----------
        bf16* qph   = (bf16*)ws;
        bf16* qkvdh = (bf16*)(ws + SZH);
        bf16* yg    = (bf16*)(ws + 2 * SZH);
        bf16* attn  = (bf16*)(ws + 2 * SZH + SZY);
        float* lp   = (float*)(ws + 2 * SZH + 2 * SZY);
        bf16* abf   = (bf16*)(ws + 2 * SZH + 2 * SZY + 1179648ull);
        float* inv  = (float*)(ws + 2 * SZH + 2 * SZY + 1179648ull + 24576ull);

        gemm48<float, bf16><<<dim3(8, 128, 4), blk, 0, stream>>>(
            x, x, 384, 384, 384, 0, 384, 384, 0, 384,
            w_bs_pw, 1, 0, 48, 0, y1, 1, 0, 48, 384, 0);
        dw3x3v<<<dim3(8, 384, 4), blk, 0, stream>>>(
            y1, w_bs_dw, yg, 0, 0, 384, 0, 384, 0, 0, 1);
        for (int h = 0; h < 8; ++h) {
            gemm48<float, bf16><<<dim3(3, 128, 4), blk, 0, stream>>>(
                x, x, 384, 384, 384, 0, 384, 384, 0, 384,
                w_qkv, 3, 384, 48, h * 48, qph, 3, 48, 0, 144, 0);
            dw3x3v<<<dim3(8, 144, 4), blk, 0, stream>>>(
                qph, w_dw, qkvdh, 1, h * 48, 144, 0, 144, 0, 0, 0);
            l2norm_v<<<dim3(2 * 4 * 48), blk, 0, stream>>>(qkvdh, inv, 4);
            qk_mfma<<<dim3(4, 8), blk, 0, stream>>>(qkvdh, lp, 4, 512);
            softmax48<<<dim3(4), blk, 0, stream>>>(lp, inv, abf, 4, 32);
            av_mfma<<<dim3(128, 4), blk, 0, stream>>>(abf, qkvdh, attn, h * 48, 384);
        }
        gemm48<bf16, float><<<dim3(8, 128, 4), blk, 0, stream>>>(
            attn, yg, 384, 768, 384, 0, 384, 384, 0, 384,
            w_proj, 1, 0, 48, 0, out, 1, 0, 48, 384, 0);
    }
}